// Round 1
// baseline (3913.419 us; speedup 1.0000x reference)
//
#include <hip/hip_runtime.h>
#include <math.h>

#define BB 64
#define EE 512
#define HH 1024
#define VV 30000
#define TT 20
#define G4 4096   // 4*H
#define KD 1024   // per-half K (2E == H == 1024)
#define NBT 469   // ceil(V/64)
#define PSTRIDE 512

// ws layout (float offsets)
#define OFF_H1  ((size_t)0)
#define OFF_C1  (OFF_H1 + BB*HH)
#define OFF_H2  (OFF_C1 + BB*HH)
#define OFF_C2  (OFF_H2 + BB*HH)
#define OFF_GP0 (OFF_C2 + BB*HH)
#define OFF_GP1 (OFF_GP0 + (size_t)BB*G4)
#define OFF_PM  (OFF_GP1 + (size_t)BB*G4)
#define OFF_PS  (OFF_PM + (size_t)BB*PSTRIDE)
#define OFF_PA  (OFF_PS + (size_t)BB*PSTRIDE)
#define OFF_LSE (OFF_PA + (size_t)BB*PSTRIDE)
#define OFF_TOK (OFF_LSE + BB)

__device__ __forceinline__ void merge3(float& m, float& s, int& a,
                                       float m2, float s2, int a2) {
    if (m2 > m) { s = s * expf(m - m2) + s2; m = m2; a = a2; }
    else if (m2 == m) { s += s2; if (a2 < a) a = a2; }
    else { s += s2 * expf(m2 - m); }
}

__global__ void k_init(float* ws) {
    int idx = blockIdx.x * 256 + threadIdx.x;
    if (idx < BB * HH * 4) ws[idx] = 0.f;                // h1,c1,h2,c2
    if (idx < BB) ((int*)(ws + OFF_TOK))[idx] = 1;       // START token
}

__global__ void k_row0(float* out) {
    int v = blockIdx.x * 256 + threadIdx.x;
    int b = blockIdx.y;
    if (v < VV) out[((size_t)b * TT) * VV + v] = (v == 1) ? 1.f : 0.f;
}

// gates: half0: A(mode) @ Wih^T + bih ; half1: Ah @ Whh^T + bhh
// mode: 0 = plain Ax; 1 = concat(img, Wemb[tok]); 2 = concat(img, 0)
__global__ __launch_bounds__(256) void k_gates(
    const float* __restrict__ Ax, const float* __restrict__ Ah,
    const float* __restrict__ img, const float* __restrict__ Wemb,
    const int* __restrict__ tok, int mode,
    const float* __restrict__ Wih, const float* __restrict__ Whh,
    const float* __restrict__ bih, const float* __restrict__ bhh,
    float* __restrict__ gp) {
    const int half = blockIdx.y;
    const float* A = half ? Ah : Ax;
    const float* W = half ? Whh : Wih;
    const float* bias = half ? bhh : bih;
    const int amode = half ? 0 : mode;
    float* out = gp + (size_t)half * (BB * G4);
    const int j0 = blockIdx.x * 32;
    __shared__ float Al[64][68];
    __shared__ float Wl[64][36];
    const int tid = threadIdx.x;
    const int jq = tid & 15;   // j = j0 + jq*2 + {0,1}
    const int bq = tid >> 4;   // b = bq*4 + {0..3}
    float acc[2][4] = {{0.f,0.f,0.f,0.f},{0.f,0.f,0.f,0.f}};

    for (int kt = 0; kt < 16; ++kt) {
        const int k0 = kt * 64;
        __syncthreads();
        // A tile: 64b x 64k
        #pragma unroll
        for (int i = 0; i < 4; ++i) {
            int f4 = tid + i * 256;
            int b  = f4 >> 4;
            int kq = (f4 & 15) << 2;
            int k  = k0 + kq;
            float4 a;
            if (amode == 0)      a = *(const float4*)&A[(size_t)b * KD + k];
            else if (k < EE)     a = *(const float4*)&img[(size_t)b * EE + k];
            else if (amode == 2) a = make_float4(0.f, 0.f, 0.f, 0.f);
            else                 a = *(const float4*)&Wemb[(size_t)tok[b] * EE + (k - EE)];
            Al[kq+0][b] = a.x; Al[kq+1][b] = a.y; Al[kq+2][b] = a.z; Al[kq+3][b] = a.w;
        }
        // W tile: 32j x 64k
        #pragma unroll
        for (int i = 0; i < 2; ++i) {
            int f4 = tid + i * 256;
            int j  = f4 >> 4;
            int kq = (f4 & 15) << 2;
            float4 w = *(const float4*)&W[(size_t)(j0 + j) * KD + k0 + kq];
            Wl[kq+0][j] = w.x; Wl[kq+1][j] = w.y; Wl[kq+2][j] = w.z; Wl[kq+3][j] = w.w;
        }
        __syncthreads();
        #pragma unroll
        for (int k = 0; k < 64; ++k) {
            float4 a4 = *(const float4*)&Al[k][bq << 2];
            float2 w2 = *(const float2*)&Wl[k][jq << 1];
            acc[0][0] += w2.x * a4.x; acc[0][1] += w2.x * a4.y;
            acc[0][2] += w2.x * a4.z; acc[0][3] += w2.x * a4.w;
            acc[1][0] += w2.y * a4.x; acc[1][1] += w2.y * a4.y;
            acc[1][2] += w2.y * a4.z; acc[1][3] += w2.y * a4.w;
        }
    }
    #pragma unroll
    for (int jj = 0; jj < 2; ++jj) {
        int j = j0 + (jq << 1) + jj;
        float bj = bias[j];
        #pragma unroll
        for (int bb2 = 0; bb2 < 4; ++bb2)
            out[(size_t)((bq << 2) + bb2) * G4 + j] = acc[jj][bb2] + bj;
    }
}

__global__ void k_upd(const float* __restrict__ gp0, const float* __restrict__ gp1,
                      float* __restrict__ h, float* __restrict__ c) {
    int idx = blockIdx.x * 256 + threadIdx.x;   // < 65536
    int b = idx >> 10, j = idx & 1023;
    const float* g0 = gp0 + (size_t)b * G4;
    const float* g1 = gp1 + (size_t)b * G4;
    float gi = g0[j]        + g1[j];
    float gf = g0[j + 1024] + g1[j + 1024];
    float gg = g0[j + 2048] + g1[j + 2048];
    float go = g0[j + 3072] + g1[j + 3072];
    float si = 1.f / (1.f + expf(-gi));
    float sf = 1.f / (1.f + expf(-gf));
    float so = 1.f / (1.f + expf(-go));
    float tg = tanhf(gg);
    float cn = sf * c[idx] + si * tg;
    float hn = so * tanhf(cn);
    c[idx] = cn; h[idx] = hn;
}

__global__ __launch_bounds__(256) void k_logits(
    const float* __restrict__ h2, const float* __restrict__ Wout,
    const float* __restrict__ bout, float* __restrict__ out, int t,
    float* __restrict__ pm, float* __restrict__ ps, int* __restrict__ pa) {
    const int v0 = blockIdx.x * 64;
    __shared__ float Al[64][68];
    __shared__ float Wl[64][68];
    const int tid = threadIdx.x;
    const int vq = tid & 15;   // v = v0 + vq*4 + {0..3}
    const int bq = tid >> 4;   // b = bq*4 + {0..3}
    float acc[4][4] = {};

    for (int kt = 0; kt < 16; ++kt) {
        const int k0 = kt * 64;
        __syncthreads();
        #pragma unroll
        for (int i = 0; i < 4; ++i) {
            int f4 = tid + i * 256;
            int b  = f4 >> 4;
            int kq = (f4 & 15) << 2;
            float4 a = *(const float4*)&h2[(size_t)b * KD + k0 + kq];
            Al[kq+0][b] = a.x; Al[kq+1][b] = a.y; Al[kq+2][b] = a.z; Al[kq+3][b] = a.w;
        }
        #pragma unroll
        for (int i = 0; i < 4; ++i) {
            int f4 = tid + i * 256;
            int j  = f4 >> 4;
            int kq = (f4 & 15) << 2;
            int row = v0 + j; if (row >= VV) row = VV - 1;  // clamp (masked later)
            float4 w = *(const float4*)&Wout[(size_t)row * KD + k0 + kq];
            Wl[kq+0][j] = w.x; Wl[kq+1][j] = w.y; Wl[kq+2][j] = w.z; Wl[kq+3][j] = w.w;
        }
        __syncthreads();
        #pragma unroll
        for (int k = 0; k < 64; ++k) {
            float4 a4 = *(const float4*)&Al[k][bq << 2];
            float4 w4 = *(const float4*)&Wl[k][vq << 2];
            acc[0][0] += w4.x * a4.x; acc[0][1] += w4.x * a4.y; acc[0][2] += w4.x * a4.z; acc[0][3] += w4.x * a4.w;
            acc[1][0] += w4.y * a4.x; acc[1][1] += w4.y * a4.y; acc[1][2] += w4.y * a4.z; acc[1][3] += w4.y * a4.w;
            acc[2][0] += w4.z * a4.x; acc[2][1] += w4.z * a4.y; acc[2][2] += w4.z * a4.z; acc[2][3] += w4.z * a4.w;
            acc[3][0] += w4.w * a4.x; acc[3][1] += w4.w * a4.y; acc[3][2] += w4.w * a4.z; acc[3][3] += w4.w * a4.w;
        }
    }
    // epilogue: bias, raw-logit write, per-b online-softmax partials
    float m[4], s[4]; int am[4];
    #pragma unroll
    for (int bb2 = 0; bb2 < 4; ++bb2) { m[bb2] = -INFINITY; s[bb2] = 0.f; am[bb2] = VV; }
    #pragma unroll
    for (int vv = 0; vv < 4; ++vv) {
        int v = v0 + (vq << 2) + vv;
        if (v < VV) {
            float bv = bout[v];
            #pragma unroll
            for (int bb2 = 0; bb2 < 4; ++bb2) {
                int b = (bq << 2) + bb2;
                float l = acc[vv][bb2] + bv;
                out[((size_t)b * TT + t) * VV + v] = l;
                merge3(m[bb2], s[bb2], am[bb2], l, 1.f, v);
            }
        }
    }
    // butterfly reduce across the 16 lanes sharing bq (lane bits 0..3)
    #pragma unroll
    for (int off = 1; off < 16; off <<= 1) {
        #pragma unroll
        for (int bb2 = 0; bb2 < 4; ++bb2) {
            float m2 = __shfl_xor(m[bb2], off, 64);
            float s2 = __shfl_xor(s[bb2], off, 64);
            int   a2 = __shfl_xor(am[bb2], off, 64);
            merge3(m[bb2], s[bb2], am[bb2], m2, s2, a2);
        }
    }
    if (vq == 0) {
        #pragma unroll
        for (int bb2 = 0; bb2 < 4; ++bb2) {
            int b = (bq << 2) + bb2;
            pm[(size_t)b * PSTRIDE + blockIdx.x] = m[bb2];
            ps[(size_t)b * PSTRIDE + blockIdx.x] = s[bb2];
            pa[(size_t)b * PSTRIDE + blockIdx.x] = am[bb2];
        }
    }
}

__global__ void k_reduce(const float* __restrict__ pm, const float* __restrict__ ps,
                         const int* __restrict__ pa, float* __restrict__ lse,
                         int* __restrict__ tok) {
    int b = blockIdx.x;
    int tid = threadIdx.x;   // 256
    float m = -INFINITY, s = 0.f; int a = VV;
    for (int i = tid; i < NBT; i += 256)
        merge3(m, s, a, pm[(size_t)b * PSTRIDE + i], ps[(size_t)b * PSTRIDE + i],
               pa[(size_t)b * PSTRIDE + i]);
    #pragma unroll
    for (int off = 1; off < 64; off <<= 1) {
        float m2 = __shfl_xor(m, off, 64);
        float s2 = __shfl_xor(s, off, 64);
        int   a2 = __shfl_xor(a, off, 64);
        merge3(m, s, a, m2, s2, a2);
    }
    __shared__ float sm[4], ss[4]; __shared__ int sa[4];
    if ((tid & 63) == 0) { sm[tid >> 6] = m; ss[tid >> 6] = s; sa[tid >> 6] = a; }
    __syncthreads();
    if (tid == 0) {
        for (int w = 1; w < 4; ++w) merge3(m, s, a, sm[w], ss[w], sa[w]);
        lse[b] = m + logf(s);
        tok[b] = a;
    }
}

__global__ void k_write(float* __restrict__ out, const float* __restrict__ lse, int t) {
    int b = blockIdx.y;
    int v = blockIdx.x * 256 + threadIdx.x;
    if (v < VV) out[((size_t)b * TT + t) * VV + v] -= lse[b];
}

extern "C" void kernel_launch(void* const* d_in, const int* in_sizes, int n_in,
                              void* d_out, int out_size, void* d_ws, size_t ws_size,
                              hipStream_t stream) {
    const float* img   = (const float*)d_in[0];
    const float* Wemb  = (const float*)d_in[1];
    const float* Wih1  = (const float*)d_in[2];
    const float* Whh1  = (const float*)d_in[3];
    const float* bih1  = (const float*)d_in[4];
    const float* bhh1  = (const float*)d_in[5];
    const float* Wih2  = (const float*)d_in[6];
    const float* Whh2  = (const float*)d_in[7];
    const float* bih2  = (const float*)d_in[8];
    const float* bhh2  = (const float*)d_in[9];
    const float* Wout  = (const float*)d_in[10];
    const float* bout  = (const float*)d_in[11];
    float* out = (float*)d_out;
    float* ws  = (float*)d_ws;

    float* h1 = ws + OFF_H1; float* c1 = ws + OFF_C1;
    float* h2 = ws + OFF_H2; float* c2 = ws + OFF_C2;
    float* gp0 = ws + OFF_GP0; float* gp1 = ws + OFF_GP1;
    float* pm = ws + OFF_PM; float* ps = ws + OFF_PS;
    int*   pa = (int*)(ws + OFF_PA);
    float* lse = ws + OFF_LSE;
    int*   tok = (int*)(ws + OFF_TOK);

    k_init<<<1024, 256, 0, stream>>>(ws);
    k_row0<<<dim3(118, 64), 256, 0, stream>>>(out);

    // pre-loop step: x0 = [img | 0]
    k_gates<<<dim3(128, 2), 256, 0, stream>>>(nullptr, h1, img, Wemb, tok, 2,
                                              Wih1, Whh1, bih1, bhh1, gp0);
    k_upd<<<256, 256, 0, stream>>>(gp0, gp1, h1, c1);
    k_gates<<<dim3(128, 2), 256, 0, stream>>>(h1, h2, img, Wemb, tok, 0,
                                              Wih2, Whh2, bih2, bhh2, gp0);
    k_upd<<<256, 256, 0, stream>>>(gp0, gp1, h2, c2);

    for (int t = 1; t < TT; ++t) {
        k_gates<<<dim3(128, 2), 256, 0, stream>>>(nullptr, h1, img, Wemb, tok, 1,
                                                  Wih1, Whh1, bih1, bhh1, gp0);
        k_upd<<<256, 256, 0, stream>>>(gp0, gp1, h1, c1);
        k_gates<<<dim3(128, 2), 256, 0, stream>>>(h1, h2, img, Wemb, tok, 0,
                                                  Wih2, Whh2, bih2, bhh2, gp0);
        k_upd<<<256, 256, 0, stream>>>(gp0, gp1, h2, c2);
        k_logits<<<NBT, 256, 0, stream>>>(h2, Wout, bout, out, t, pm, ps, pa);
        k_reduce<<<64, 256, 0, stream>>>(pm, ps, pa, lse, tok);
        k_write<<<dim3(118, 64), 256, 0, stream>>>(out, lse, t);
    }
}

// Round 2
// 3242.055 us; speedup vs baseline: 1.2071x; 1.2071x over previous
//
#include <hip/hip_runtime.h>
#include <math.h>

#define BB 64
#define EE 512
#define HH 1024
#define VV 30000
#define TT 20
#define NBT 469
#define PSTRIDE 512

typedef __attribute__((ext_vector_type(8))) short bf16x8;
typedef __attribute__((ext_vector_type(4))) float f32x4;
typedef __attribute__((ext_vector_type(4))) int i32x4;

// ---- ws byte offsets ----
#define WS_C1   0u
#define WS_C2   262144u
#define WS_X1HI 524288u
#define WS_X1LO 655360u
#define WS_H0   786432u      // bank0: H1hi,H1lo,H2hi,H2lo (131072 each)
#define WS_H1   1310720u     // bank1
#define WS_BSUM 1835008u
#define WS_PM   1867776u
#define WS_PS   1998848u
#define WS_PA   2129920u
#define WS_LSE  2260992u
#define WS_TOK  2261248u
#define HB_HI1 0u
#define HB_LO1 131072u
#define HB_HI2 262144u
#define HB_LO2 393216u

__device__ __forceinline__ unsigned short bf_hi(float x) {
    unsigned u = __float_as_uint(x);
    return (unsigned short)((u + 0x7fffu + ((u >> 16) & 1u)) >> 16);
}
__device__ __forceinline__ float bf_f(unsigned short h) {
    return __uint_as_float(((unsigned)h) << 16);
}

__device__ __forceinline__ void merge3(float& m, float& s, int& a,
                                       float m2, float s2, int a2) {
    if (m2 > m) { s = s * expf(m - m2) + s2; m = m2; a = a2; }
    else if (m2 == m) { s += s2; if (a2 < a) a = a2; }
    else { s += s2 * expf(m2 - m); }
}

// ---------------- prep: zero states, convert img, bias sums, tok=START ----
__global__ void k_prep(float* ws, const float* __restrict__ img,
                       const float* __restrict__ bih1, const float* __restrict__ bhh1,
                       const float* __restrict__ bih2, const float* __restrict__ bhh2) {
    unsigned idx = blockIdx.x * 256 + threadIdx.x;
    char* wsb = (char*)ws;
    unsigned* w32 = (unsigned*)ws;
    if (idx < 131072) { w32[idx] = 0u; return; }              // c1,c2 = 0
    idx -= 131072;
    if (idx < 32768) {                                        // X1 emb-half = 0
        unsigned buf = idx >> 14, e = idx & 16383;
        unsigned row = e >> 8, col = e & 255;
        unsigned base = (buf ? WS_X1LO : WS_X1HI) / 4;
        w32[base + row * 512 + 256 + col] = 0u; return;
    }
    idx -= 32768;
    if (idx < 32768) {                                        // img -> hi/lo bf16
        unsigned b = idx >> 9, k = idx & 511;
        float x = img[b * 512 + k];
        unsigned short hi = bf_hi(x);
        unsigned short lo = bf_hi(x - bf_f(hi));
        ((unsigned short*)(wsb + WS_X1HI))[b * 1024 + k] = hi;
        ((unsigned short*)(wsb + WS_X1LO))[b * 1024 + k] = lo;
        return;
    }
    idx -= 32768;
    if (idx < 131072) { ((unsigned*)(wsb + WS_H0))[idx] = 0u; return; }  // h bank0 = 0
    idx -= 131072;
    if (idx < 8192) {                                         // bias sums
        float v = (idx < 4096) ? bih1[idx] + bhh1[idx] : bih2[idx - 4096] + bhh2[idx - 4096];
        ((float*)(wsb + WS_BSUM))[idx] = v; return;
    }
    idx -= 8192;
    if (idx < 64) ((int*)(wsb + WS_TOK))[idx] = 1;
}

__global__ void k_row0(float* out) {
    int v = blockIdx.x * 256 + threadIdx.x;
    int b = blockIdx.y;
    if (v < VV) out[((size_t)b * TT) * VV + v] = (v == 1) ? 1.f : 0.f;
}

// ---------------- embedding gather + split ----------------
__global__ void k_emb(float* ws, const float* __restrict__ Wemb) {
    int b = blockIdx.x, t = threadIdx.x;   // 128 threads
    char* wsb = (char*)ws;
    int tok = ((const int*)(wsb + WS_TOK))[b];
    f32x4 v = *(const f32x4*)&Wemb[(size_t)tok * EE + t * 4];
    unsigned short h0 = bf_hi(v[0]), h1 = bf_hi(v[1]), h2 = bf_hi(v[2]), h3 = bf_hi(v[3]);
    unsigned short l0 = bf_hi(v[0] - bf_f(h0)), l1 = bf_hi(v[1] - bf_f(h1));
    unsigned short l2 = bf_hi(v[2] - bf_f(h2)), l3 = bf_hi(v[3] - bf_f(h3));
    uint2 hv; hv.x = h0 | ((unsigned)h1 << 16); hv.y = h2 | ((unsigned)h3 << 16);
    uint2 lv; lv.x = l0 | ((unsigned)l1 << 16); lv.y = l2 | ((unsigned)l3 << 16);
    size_t e = (size_t)b * 1024 + 512 + t * 4;
    *(uint2*)(wsb + WS_X1HI + e * 2) = hv;
    *(uint2*)(wsb + WS_X1LO + e * 2) = lv;
}

// ---------------- fused LSTM cell (gates MFMA + activations) -------------
// block: 16 h-rows x 64 b; 4 waves = 4 gates; K = 2048 (x half + h half)
__global__ __launch_bounds__(256) void k_cell(
    const unsigned short* __restrict__ Axhi, const unsigned short* __restrict__ Axlo,
    const unsigned short* __restrict__ Ahhi, const unsigned short* __restrict__ Ahlo,
    const float* __restrict__ Wih, const float* __restrict__ Whh,
    const float* __restrict__ bsumc, float* __restrict__ c,
    unsigned short* __restrict__ Hohi, unsigned short* __restrict__ Holo)
{
    __shared__ char smem[65536];   // dbuf: [Whi 8K][Wlo 8K][Ahi 8K][Alo 8K] x2
    const int tid = threadIdx.x;
    const int l = tid & 63, w = tid >> 6;
    const int g = l >> 4, n = l & 15;
    const int hb = blockIdx.x * 16;

    f32x4 acc[4];
    #pragma unroll
    for (int i = 0; i < 4; ++i) acc[i] = (f32x4){0.f, 0.f, 0.f, 0.f};
    f32x4 wreg[4];
    i32x4 areg[4];

    const int kq = tid & 15, rr = tid >> 4;
    const int k8 = tid & 7, brow = tid >> 3;
    const int ws_ = kq >> 3, gw = (kq >> 1) & 3, half = kq & 1;
    const int s4gw = ws_ * 4 + gw;
    const int s2 = k8 >> 2, g2 = k8 & 3;

    auto stage_issue = [&](int kt) {
        const float* Wm = (kt < 16) ? Wih : Whh;
        const unsigned short* Ah = (kt < 16) ? Axhi : Ahhi;
        const unsigned short* Al = (kt < 16) ? Axlo : Ahlo;
        int k0 = (kt & 15) * 64;
        #pragma unroll
        for (int i = 0; i < 4; ++i)
            wreg[i] = *(const f32x4*)&Wm[(size_t)(i * 1024 + hb + rr) * 1024 + k0 + kq * 4];
        areg[0] = *(const i32x4*)&Ah[(size_t)brow * 1024 + k0 + k8 * 8];
        areg[1] = *(const i32x4*)&Ah[(size_t)(brow + 32) * 1024 + k0 + k8 * 8];
        areg[2] = *(const i32x4*)&Al[(size_t)brow * 1024 + k0 + k8 * 8];
        areg[3] = *(const i32x4*)&Al[(size_t)(brow + 32) * 1024 + k0 + k8 * 8];
    };
    auto stage_write = [&](int buf) {
        char* bw = smem + buf * 32768;
        #pragma unroll
        for (int i = 0; i < 4; ++i) {
            int chunk = ((ws_ * 4 + i) * 4 + gw) * 16 + (rr ^ s4gw);
            unsigned short h0 = bf_hi(wreg[i][0]), h1 = bf_hi(wreg[i][1]);
            unsigned short h2 = bf_hi(wreg[i][2]), h3 = bf_hi(wreg[i][3]);
            unsigned short q0 = bf_hi(wreg[i][0] - bf_f(h0)), q1 = bf_hi(wreg[i][1] - bf_f(h1));
            unsigned short q2 = bf_hi(wreg[i][2] - bf_f(h2)), q3 = bf_hi(wreg[i][3] - bf_f(h3));
            uint2 hv; hv.x = h0 | ((unsigned)h1 << 16); hv.y = h2 | ((unsigned)h3 << 16);
            uint2 lv; lv.x = q0 | ((unsigned)q1 << 16); lv.y = q2 | ((unsigned)q3 << 16);
            *(uint2*)(bw + chunk * 16 + half * 8) = hv;
            *(uint2*)(bw + 8192 + chunk * 16 + half * 8) = lv;
        }
        #pragma unroll
        for (int i = 0; i < 2; ++i) {
            int b2 = brow + 32 * i;
            int chunk = s2 * 256 + (b2 >> 4) * 64 + g2 * 16 + (b2 & 15);
            *(i32x4*)(bw + 16384 + chunk * 16) = areg[i];
            *(i32x4*)(bw + 24576 + chunk * 16) = areg[2 + i];
        }
    };

    stage_issue(0); stage_write(0); __syncthreads();
    for (int kt = 0; kt < 32; ++kt) {
        if (kt + 1 < 32) stage_issue(kt + 1);
        char* bw = smem + (kt & 1) * 32768;
        char* ba = bw + 16384;
        #pragma unroll
        for (int s = 0; s < 2; ++s) {
            int s4g = s * 4 + g;
            int wc = ((s * 4 + w) * 4 + g) * 16 + (n ^ s4g);
            bf16x8 ah = *(const bf16x8*)(bw + wc * 16);
            bf16x8 al = *(const bf16x8*)(bw + 8192 + wc * 16);
            #pragma unroll
            for (int bg = 0; bg < 4; ++bg) {
                int ac = s * 256 + bg * 64 + g * 16 + n;
                bf16x8 bh = *(const bf16x8*)(ba + ac * 16);
                bf16x8 bl = *(const bf16x8*)(ba + 8192 + ac * 16);
                acc[bg] = __builtin_amdgcn_mfma_f32_16x16x32_bf16(ah, bh, acc[bg], 0, 0, 0);
                acc[bg] = __builtin_amdgcn_mfma_f32_16x16x32_bf16(ah, bl, acc[bg], 0, 0, 0);
                acc[bg] = __builtin_amdgcn_mfma_f32_16x16x32_bf16(al, bh, acc[bg], 0, 0, 0);
            }
        }
        if (kt + 1 < 32) stage_write((kt + 1) & 1);
        __syncthreads();
    }
    // epilogue: gates -> LDS, then cell update
    float* gl = (float*)smem;   // [4 gates][16 j][64 b]
    #pragma unroll
    for (int bg = 0; bg < 4; ++bg)
        #pragma unroll
        for (int p = 0; p < 4; ++p)
            gl[w * 1024 + (g * 4 + p) * 64 + bg * 16 + n] = acc[bg][p];
    __syncthreads();
    #pragma unroll
    for (int i = 0; i < 4; ++i) {
        int e = tid + 256 * i;
        int b = e & 63, j = e >> 6;
        float gi = gl[        j * 64 + b] + bsumc[       hb + j];
        float gf = gl[1024 +  j * 64 + b] + bsumc[1024 + hb + j];
        float gg = gl[2048 +  j * 64 + b] + bsumc[2048 + hb + j];
        float go = gl[3072 +  j * 64 + b] + bsumc[3072 + hb + j];
        float si = 1.f / (1.f + expf(-gi));
        float sf = 1.f / (1.f + expf(-gf));
        float so = 1.f / (1.f + expf(-go));
        int ci = b * 1024 + hb + j;
        float cn = sf * c[ci] + si * tanhf(gg);
        float hn = so * tanhf(cn);
        c[ci] = cn;
        unsigned short hi = bf_hi(hn);
        unsigned short lo = bf_hi(hn - bf_f(hi));
        Hohi[ci] = hi; Holo[ci] = lo;
    }
}

// ---------------- logits MFMA: C[64v x 64b] per block, K=1024 ------------
__global__ __launch_bounds__(256) void k_logits(
    const float* __restrict__ Wout, const float* __restrict__ bout,
    const unsigned short* __restrict__ h2hi, const unsigned short* __restrict__ h2lo,
    float* __restrict__ out, int tstep,
    float* __restrict__ pm, float* __restrict__ ps, int* __restrict__ pa)
{
    __shared__ char smem[65536];
    const int tid = threadIdx.x;
    const int l = tid & 63, w = tid >> 6;
    const int g = l >> 4, n = l & 15;
    const int v0 = blockIdx.x * 64;

    f32x4 acc[4];
    #pragma unroll
    for (int i = 0; i < 4; ++i) acc[i] = (f32x4){0.f, 0.f, 0.f, 0.f};
    f32x4 wreg[4];
    i32x4 areg[4];

    const int kq = tid & 15, rr = tid >> 4;
    const int k8 = tid & 7, brow = tid >> 3;
    const int ws_ = kq >> 3, gw = (kq >> 1) & 3, half = kq & 1;
    const int s4gw = ws_ * 4 + gw;
    const int s2 = k8 >> 2, g2 = k8 & 3;

    auto stage_issue = [&](int kt) {
        int k0 = kt * 64;
        #pragma unroll
        for (int i = 0; i < 4; ++i) {
            int row = v0 + rr + 16 * i; if (row > VV - 1) row = VV - 1;
            wreg[i] = *(const f32x4*)&Wout[(size_t)row * 1024 + k0 + kq * 4];
        }
        areg[0] = *(const i32x4*)&h2hi[(size_t)brow * 1024 + k0 + k8 * 8];
        areg[1] = *(const i32x4*)&h2hi[(size_t)(brow + 32) * 1024 + k0 + k8 * 8];
        areg[2] = *(const i32x4*)&h2lo[(size_t)brow * 1024 + k0 + k8 * 8];
        areg[3] = *(const i32x4*)&h2lo[(size_t)(brow + 32) * 1024 + k0 + k8 * 8];
    };
    auto stage_write = [&](int buf) {
        char* bw = smem + buf * 32768;
        #pragma unroll
        for (int i = 0; i < 4; ++i) {
            int chunk = ((ws_ * 4 + i) * 4 + gw) * 16 + (rr ^ s4gw);
            unsigned short h0 = bf_hi(wreg[i][0]), h1 = bf_hi(wreg[i][1]);
            unsigned short h2 = bf_hi(wreg[i][2]), h3 = bf_hi(wreg[i][3]);
            unsigned short q0 = bf_hi(wreg[i][0] - bf_f(h0)), q1 = bf_hi(wreg[i][1] - bf_f(h1));
            unsigned short q2 = bf_hi(wreg[i][2] - bf_f(h2)), q3 = bf_hi(wreg[i][3] - bf_f(h3));
            uint2 hv; hv.x = h0 | ((unsigned)h1 << 16); hv.y = h2 | ((unsigned)h3 << 16);
            uint2 lv; lv.x = q0 | ((unsigned)q1 << 16); lv.y = q2 | ((unsigned)q3 << 16);
            *(uint2*)(bw + chunk * 16 + half * 8) = hv;
            *(uint2*)(bw + 8192 + chunk * 16 + half * 8) = lv;
        }
        #pragma unroll
        for (int i = 0; i < 2; ++i) {
            int b2 = brow + 32 * i;
            int chunk = s2 * 256 + (b2 >> 4) * 64 + g2 * 16 + (b2 & 15);
            *(i32x4*)(bw + 16384 + chunk * 16) = areg[i];
            *(i32x4*)(bw + 24576 + chunk * 16) = areg[2 + i];
        }
    };

    stage_issue(0); stage_write(0); __syncthreads();
    for (int kt = 0; kt < 16; ++kt) {
        if (kt + 1 < 16) stage_issue(kt + 1);
        char* bw = smem + (kt & 1) * 32768;
        char* ba = bw + 16384;
        #pragma unroll
        for (int s = 0; s < 2; ++s) {
            int s4g = s * 4 + g;
            int wc = ((s * 4 + w) * 4 + g) * 16 + (n ^ s4g);
            bf16x8 ah = *(const bf16x8*)(bw + wc * 16);
            bf16x8 al = *(const bf16x8*)(bw + 8192 + wc * 16);
            #pragma unroll
            for (int bg = 0; bg < 4; ++bg) {
                int ac = s * 256 + bg * 64 + g * 16 + n;
                bf16x8 bh = *(const bf16x8*)(ba + ac * 16);
                bf16x8 bl = *(const bf16x8*)(ba + 8192 + ac * 16);
                acc[bg] = __builtin_amdgcn_mfma_f32_16x16x32_bf16(ah, bh, acc[bg], 0, 0, 0);
                acc[bg] = __builtin_amdgcn_mfma_f32_16x16x32_bf16(ah, bl, acc[bg], 0, 0, 0);
                acc[bg] = __builtin_amdgcn_mfma_f32_16x16x32_bf16(al, bh, acc[bg], 0, 0, 0);
            }
        }
        if (kt + 1 < 16) stage_write((kt + 1) & 1);
        __syncthreads();
    }

    // epilogue: bias, transpose through LDS, coalesced store, softmax partials
    int bidx = v0 + w * 16 + g * 4; if (bidx > VV - 4) bidx = VV - 4;
    f32x4 bb = *(const f32x4*)&bout[bidx];
    float* gl = (float*)smem;   // [64 b][68]
    #pragma unroll
    for (int bg = 0; bg < 4; ++bg)
        #pragma unroll
        for (int p = 0; p < 4; ++p)
            gl[(bg * 16 + n) * 68 + w * 16 + g * 4 + p] = acc[bg][p] + bb[p];
    __syncthreads();

    int b = tid >> 2, vq = tid & 3;
    float m = -INFINITY, ssum = 0.f; int am = VV;
    if (v0 + vq * 16 < VV) {
        size_t ob = ((size_t)b * TT + tstep) * VV + v0 + vq * 16;
        #pragma unroll
        for (int e4 = 0; e4 < 4; ++e4) {
            f32x4 vv = *(const f32x4*)&gl[b * 68 + vq * 16 + e4 * 4];
            *(f32x4*)&out[ob + e4 * 4] = vv;
            #pragma unroll
            for (int p = 0; p < 4; ++p)
                merge3(m, ssum, am, vv[p], 1.f, v0 + vq * 16 + e4 * 4 + p);
        }
    }
    #pragma unroll
    for (int off = 1; off < 4; off <<= 1) {
        float m2 = __shfl_xor(m, off, 64);
        float s2_ = __shfl_xor(ssum, off, 64);
        int a2 = __shfl_xor(am, off, 64);
        merge3(m, ssum, am, m2, s2_, a2);
    }
    if (vq == 0) {
        pm[b * PSTRIDE + blockIdx.x] = m;
        ps[b * PSTRIDE + blockIdx.x] = ssum;
        pa[b * PSTRIDE + blockIdx.x] = am;
    }
}

__global__ void k_reduce(const float* __restrict__ pm, const float* __restrict__ ps,
                         const int* __restrict__ pa, float* __restrict__ lse,
                         int* __restrict__ tok) {
    int b = blockIdx.x;
    int tid = threadIdx.x;   // 256
    float m = -INFINITY, s = 0.f; int a = VV;
    for (int i = tid; i < NBT; i += 256)
        merge3(m, s, a, pm[(size_t)b * PSTRIDE + i], ps[(size_t)b * PSTRIDE + i],
               pa[(size_t)b * PSTRIDE + i]);
    #pragma unroll
    for (int off = 1; off < 64; off <<= 1) {
        float m2 = __shfl_xor(m, off, 64);
        float s2 = __shfl_xor(s, off, 64);
        int   a2 = __shfl_xor(a, off, 64);
        merge3(m, s, a, m2, s2, a2);
    }
    __shared__ float sm[4], ss[4]; __shared__ int sa[4];
    if ((tid & 63) == 0) { sm[tid >> 6] = m; ss[tid >> 6] = s; sa[tid >> 6] = a; }
    __syncthreads();
    if (tid == 0) {
        for (int w = 1; w < 4; ++w) merge3(m, s, a, sm[w], ss[w], sa[w]);
        lse[b] = m + logf(s);
        tok[b] = a;
    }
}

__global__ void k_write(float* __restrict__ out, const float* __restrict__ lse, int t) {
    int b = blockIdx.y;
    int v = blockIdx.x * 256 + threadIdx.x;
    if (v < VV) out[((size_t)b * TT + t) * VV + v] -= lse[b];
}

extern "C" void kernel_launch(void* const* d_in, const int* in_sizes, int n_in,
                              void* d_out, int out_size, void* d_ws, size_t ws_size,
                              hipStream_t stream) {
    const float* img   = (const float*)d_in[0];
    const float* Wemb  = (const float*)d_in[1];
    const float* Wih1  = (const float*)d_in[2];
    const float* Whh1  = (const float*)d_in[3];
    const float* bih1  = (const float*)d_in[4];
    const float* bhh1  = (const float*)d_in[5];
    const float* Wih2  = (const float*)d_in[6];
    const float* Whh2  = (const float*)d_in[7];
    const float* bih2  = (const float*)d_in[8];
    const float* bhh2  = (const float*)d_in[9];
    const float* Wout  = (const float*)d_in[10];
    const float* bout  = (const float*)d_in[11];
    float* out = (float*)d_out;
    float* ws  = (float*)d_ws;
    char*  wsb = (char*)d_ws;

    float* c1   = (float*)(wsb + WS_C1);
    float* c2   = (float*)(wsb + WS_C2);
    float* bsum = (float*)(wsb + WS_BSUM);
    float* pm   = (float*)(wsb + WS_PM);
    float* ps   = (float*)(wsb + WS_PS);
    int*   pa   = (int*)(wsb + WS_PA);
    float* lse  = (float*)(wsb + WS_LSE);
    int*   tok  = (int*)(wsb + WS_TOK);
    unsigned short* X1hi = (unsigned short*)(wsb + WS_X1HI);
    unsigned short* X1lo = (unsigned short*)(wsb + WS_X1LO);
    auto Hb = [&](int bank, unsigned off) {
        return (unsigned short*)(wsb + (bank ? WS_H1 : WS_H0) + off);
    };

    k_prep<<<1313, 256, 0, stream>>>(ws, img, bih1, bhh1, bih2, bhh2);
    k_row0<<<dim3(118, 64), 256, 0, stream>>>(out);

    int cur = 0;
    // pre-loop step (emb half of X1 is zero)
    k_cell<<<64, 256, 0, stream>>>(X1hi, X1lo, Hb(cur, HB_HI1), Hb(cur, HB_LO1),
                                   Wih1, Whh1, bsum, c1,
                                   Hb(cur ^ 1, HB_HI1), Hb(cur ^ 1, HB_LO1));
    k_cell<<<64, 256, 0, stream>>>(Hb(cur ^ 1, HB_HI1), Hb(cur ^ 1, HB_LO1),
                                   Hb(cur, HB_HI2), Hb(cur, HB_LO2),
                                   Wih2, Whh2, bsum + 4096, c2,
                                   Hb(cur ^ 1, HB_HI2), Hb(cur ^ 1, HB_LO2));
    cur ^= 1;

    for (int t = 1; t < TT; ++t) {
        k_emb<<<64, 128, 0, stream>>>(ws, Wemb);
        k_cell<<<64, 256, 0, stream>>>(X1hi, X1lo, Hb(cur, HB_HI1), Hb(cur, HB_LO1),
                                       Wih1, Whh1, bsum, c1,
                                       Hb(cur ^ 1, HB_HI1), Hb(cur ^ 1, HB_LO1));
        k_cell<<<64, 256, 0, stream>>>(Hb(cur ^ 1, HB_HI1), Hb(cur ^ 1, HB_LO1),
                                       Hb(cur, HB_HI2), Hb(cur, HB_LO2),
                                       Wih2, Whh2, bsum + 4096, c2,
                                       Hb(cur ^ 1, HB_HI2), Hb(cur ^ 1, HB_LO2));
        k_logits<<<NBT, 256, 0, stream>>>(Wout, bout,
                                          Hb(cur ^ 1, HB_HI2), Hb(cur ^ 1, HB_LO2),
                                          out, t, pm, ps, pa);
        k_reduce<<<64, 256, 0, stream>>>(pm, ps, pa, lse, tok);
        k_write<<<dim3(118, 64), 256, 0, stream>>>(out, lse, t);
        cur ^= 1;
    }
}

// Round 3
// 1268.508 us; speedup vs baseline: 3.0851x; 2.5558x over previous
//
#include <hip/hip_runtime.h>
#include <math.h>

#define BB 64
#define EE 512
#define HH 1024
#define VV 30000
#define TT 20
#define NBT 469
#define PSTRIDE 512

typedef __attribute__((ext_vector_type(8))) short bf16x8;
typedef __attribute__((ext_vector_type(4))) float f32x4;

// ---- ws byte offsets ----
#define OFF_W1  ((size_t)0)
#define OFF_W2  ((size_t)33554432)
#define OFF_WO  ((size_t)67108864)
#define OFF_X1  ((size_t)190054400)
#define OFF_H1  ((size_t)190316544)   // + bank*262144
#define OFF_H2  ((size_t)190840832)   // + bank*262144
#define OFF_C1  ((size_t)191365120)
#define OFF_C2  ((size_t)191627264)
#define OFF_P   ((size_t)191889408)   // 4 MB: [kq][4096][64] f32
#define OFF_PM  ((size_t)196083712)
#define OFF_PS  ((size_t)196214784)
#define OFF_PA  ((size_t)196345856)
#define OFF_LSE ((size_t)196476928)   // [20][64] f32
#define OFF_BS  ((size_t)196482048)   // 8192 f32

__device__ __forceinline__ unsigned short bf_hi(float x) {
    unsigned u = __float_as_uint(x);
    return (unsigned short)((u + 0x7fffu + ((u >> 16) & 1u)) >> 16);
}
__device__ __forceinline__ float bf_f(unsigned short h) {
    return __uint_as_float(((unsigned)h) << 16);
}
__device__ __forceinline__ void merge3(float& m, float& s, int& a,
                                       float m2, float s2, int a2) {
    if (m2 > m) { s = s * expf(m - m2) + s2; m = m2; a = a2; }
    else if (m2 == m) { s += s2; if (a2 < a) a = a2; }
    else { s += s2 * expf(m2 - m); }
}
__device__ __forceinline__ void gl16(const void* g, void* l) {
    __builtin_amdgcn_global_load_lds(
        (const unsigned int __attribute__((address_space(1)))*)g,
        (unsigned int __attribute__((address_space(3)))*)l, 16, 0, 0);
}
// convert 8 consecutive fp32 -> hi 16B + lo 16B
__device__ __forceinline__ void cvt8(const float* src, uint4& hv, uint4& lv) {
    unsigned h[8], q[8];
    #pragma unroll
    for (int i = 0; i < 8; ++i) {
        float x = src[i];
        unsigned short hi = bf_hi(x);
        unsigned short lo = bf_hi(x - bf_f(hi));
        h[i] = hi; q[i] = lo;
    }
    hv.x = h[0] | (h[1] << 16); hv.y = h[2] | (h[3] << 16);
    hv.z = h[4] | (h[5] << 16); hv.w = h[6] | (h[7] << 16);
    lv.x = q[0] | (q[1] << 16); lv.y = q[2] | (q[3] << 16);
    lv.z = q[4] | (q[5] << 16); lv.w = q[6] | (q[7] << 16);
}

// ---------------- one-time weight conversion into chunk layout ----------------
// chunk c (0..511): s=c>>8, bg=(c>>6)&3, g=(c>>4)&3, n=c&15
//   row_local = bg*16+n, k_local = s*32+g*8
__global__ __launch_bounds__(256) void k_conv_cell(
    const float* __restrict__ Wih1, const float* __restrict__ Whh1,
    const float* __restrict__ Wih2, const float* __restrict__ Whh2, char* wsb) {
    int cell = blockIdx.y;
    const float* Wih = cell ? Wih2 : Wih1;
    const float* Whh = cell ? Whh2 : Whh1;
    char* dst = wsb + (cell ? OFF_W2 : OFF_W1);
    unsigned flat = blockIdx.x * 256 + threadIdx.x;  // < 64*32*512
    unsigned c = flat & 511, kt = (flat >> 9) & 31, rt = flat >> 14;
    unsigned s = c >> 8, bg = (c >> 6) & 3, g = (c >> 4) & 3, n = c & 15;
    unsigned row = bg * 1024 + rt * 16 + n;
    unsigned col = (kt & 15) * 64 + s * 32 + g * 8;
    const float* src = (kt < 16 ? Wih : Whh) + (size_t)row * 1024 + col;
    uint4 hv, lv; cvt8(src, hv, lv);
    char* d = dst + (size_t)rt * 524288 + kt * 16384 + c * 16;
    *(uint4*)d = hv;
    *(uint4*)(d + 8192) = lv;
}

__global__ __launch_bounds__(256) void k_conv_out(const float* __restrict__ Wout,
                                                  char* wsb) {
    unsigned flat = blockIdx.x * 256 + threadIdx.x;  // < 469*16*512
    unsigned c = flat & 511, kt = (flat >> 9) & 15, rt = flat >> 13;
    unsigned s = c >> 8, bg = (c >> 6) & 3, g = (c >> 4) & 3, n = c & 15;
    unsigned row = rt * 64 + bg * 16 + n; if (row > VV - 1) row = VV - 1;
    unsigned col = kt * 64 + s * 32 + g * 8;
    const float* src = Wout + (size_t)row * 1024 + col;
    uint4 hv, lv; cvt8(src, hv, lv);
    char* d = wsb + OFF_WO + (size_t)rt * 262144 + kt * 16384 + c * 16;
    *(uint4*)d = hv;
    *(uint4*)(d + 8192) = lv;
}

__global__ __launch_bounds__(256) void k_conv_img(const float* __restrict__ img,
                                                  char* wsb) {
    unsigned flat = blockIdx.x * 256 + threadIdx.x;  // < 8*512
    unsigned c = flat & 511, kt = flat >> 9;
    unsigned s = c >> 8, bg = (c >> 6) & 3, g = (c >> 4) & 3, n = c & 15;
    unsigned b = bg * 16 + n;
    unsigned col = kt * 64 + s * 32 + g * 8;
    const float* src = img + (size_t)b * 512 + col;
    uint4 hv, lv; cvt8(src, hv, lv);
    char* d = wsb + OFF_X1 + kt * 16384 + c * 16;
    *(uint4*)d = hv;
    *(uint4*)(d + 8192) = lv;
}

// ---------------- prep: zeros + bias sums ----------------
__global__ void k_prep(char* wsb,
                       const float* __restrict__ bih1, const float* __restrict__ bhh1,
                       const float* __restrict__ bih2, const float* __restrict__ bhh2) {
    unsigned idx = blockIdx.x * 256 + threadIdx.x;
    if (idx < 131072) { ((unsigned*)(wsb + OFF_C1))[idx] = 0u; return; }   // c1,c2
    idx -= 131072;
    if (idx < 65536) { ((unsigned*)(wsb + OFF_H1))[idx] = 0u; return; }    // H1 bank0
    idx -= 65536;
    if (idx < 65536) { ((unsigned*)(wsb + OFF_H2))[idx] = 0u; return; }    // H2 bank0
    idx -= 65536;
    if (idx < 32768) { ((unsigned*)(wsb + OFF_X1 + 131072))[idx] = 0u; return; } // X1 emb
    idx -= 32768;
    if (idx < 8192) {
        float v = (idx < 4096) ? bih1[idx] + bhh1[idx]
                               : bih2[idx - 4096] + bhh2[idx - 4096];
        ((float*)(wsb + OFF_BS))[idx] = v;
    }
}

// ---------------- emb writer (shared helper) ----------------
__device__ __forceinline__ void emb_write(char* X1, const float* Wemb, int tk,
                                          int b, int tid) {
    #pragma unroll
    for (int i = 0; i < 2; ++i) {
        int e = tid + i * 256;
        float x = Wemb[(size_t)tk * 512 + e];
        unsigned short hi = bf_hi(x);
        unsigned short lo = bf_hi(x - bf_f(hi));
        int k = 512 + e;
        int kt = k >> 6, kl = k & 63;
        int s = kl >> 5, gq = (kl >> 3) & 3, off = kl & 7;
        int chunk = s * 256 + (b >> 4) * 64 + gq * 16 + (b & 15);
        char* d = X1 + kt * 16384 + chunk * 16 + off * 2;
        *(unsigned short*)d = hi;
        *(unsigned short*)(d + 8192) = lo;
    }
}

__global__ void k_emb0(const float* __restrict__ Wemb, char* wsb) {
    emb_write(wsb + OFF_X1, Wemb, 1, blockIdx.x, threadIdx.x);  // START=1
}

// ---------------- gemm core: 64 rows x 64 b, NKT k-tiles of 64 ----------------
template <int NKT>
__device__ __forceinline__ void gemm_core(const char* __restrict__ Wsrc,
                                          const char* __restrict__ Asrc,
                                          char* smem, int tid, f32x4 acc[4]) {
    const int l = tid & 63, w = tid >> 6, g = l >> 4, n = l & 15;
    auto stage = [&](int kt, char* buf) {
        const char* wsp = Wsrc + kt * 16384;
        const char* asp = Asrc + kt * 16384;
        int o = tid * 16;
        gl16(wsp + o, buf + o);
        gl16(wsp + 4096 + o, buf + 4096 + o);
        gl16(wsp + 8192 + o, buf + 8192 + o);
        gl16(wsp + 12288 + o, buf + 12288 + o);
        gl16(asp + o, buf + 16384 + o);
        gl16(asp + 4096 + o, buf + 20480 + o);
        gl16(asp + 8192 + o, buf + 24576 + o);
        gl16(asp + 12288 + o, buf + 28672 + o);
    };
    stage(0, smem);
    __syncthreads();
    for (int kt = 0; kt < NKT; ++kt) {
        char* buf = smem + (kt & 1) * 32768;
        if (kt + 1 < NKT) stage(kt + 1, smem + ((kt + 1) & 1) * 32768);
        #pragma unroll
        for (int s = 0; s < 2; ++s) {
            int wc = (s * 256 + w * 64 + g * 16 + n) * 16;
            bf16x8 ah = *(const bf16x8*)(buf + wc);
            bf16x8 al = *(const bf16x8*)(buf + 8192 + wc);
            #pragma unroll
            for (int bg = 0; bg < 4; ++bg) {
                int ac = (s * 256 + bg * 64 + g * 16 + n) * 16;
                bf16x8 bh = *(const bf16x8*)(buf + 16384 + ac);
                bf16x8 bl = *(const bf16x8*)(buf + 24576 + ac);
                acc[bg] = __builtin_amdgcn_mfma_f32_16x16x32_bf16(ah, bh, acc[bg], 0, 0, 0);
                acc[bg] = __builtin_amdgcn_mfma_f32_16x16x32_bf16(ah, bl, acc[bg], 0, 0, 0);
                acc[bg] = __builtin_amdgcn_mfma_f32_16x16x32_bf16(al, bh, acc[bg], 0, 0, 0);
            }
        }
        __syncthreads();
    }
}

// ---------------- cell gates GEMM, split-K x4 ----------------
__global__ __launch_bounds__(256) void k_cellg(const char* __restrict__ Wbase,
                                               const char* __restrict__ Ax,
                                               const char* __restrict__ Ah,
                                               float* __restrict__ P) {
    __shared__ __align__(16) char smem[65536];
    const int tid = threadIdx.x;
    const int rt = blockIdx.x & 63, kq = blockIdx.x >> 6;
    const char* Wsrc = Wbase + (size_t)rt * 524288 + kq * 131072;
    const char* Asrc = (kq < 2) ? Ax + kq * 131072 : Ah + (kq - 2) * 131072;
    f32x4 acc[4];
    #pragma unroll
    for (int i = 0; i < 4; ++i) acc[i] = (f32x4){0.f, 0.f, 0.f, 0.f};
    gemm_core<8>(Wsrc, Asrc, smem, tid, acc);
    const int l = tid & 63, w = tid >> 6, g = l >> 4, n = l & 15;
    float* Pd = P + kq * 262144 + rt * 4096;
    #pragma unroll
    for (int bg = 0; bg < 4; ++bg)
        #pragma unroll
        for (int p = 0; p < 4; ++p)
            Pd[(w * 16 + g * 4 + p) * 64 + bg * 16 + n] = acc[bg][p];
}

// ---------------- activation: sum partials, LSTM update, write H swz ----------
__global__ void k_act(const float* __restrict__ P, const float* __restrict__ bs,
                      float* __restrict__ c, char* __restrict__ Hdst) {
    int rt = blockIdx.x, bq = blockIdx.y;
    int jl = threadIdx.x >> 4, bl = threadIdx.x & 15;
    int b = bq * 16 + bl;
    int base = rt * 4096;
    float g4[4];
    #pragma unroll
    for (int gg = 0; gg < 4; ++gg) {
        float v = 0.f;
        #pragma unroll
        for (int kq = 0; kq < 4; ++kq)
            v += P[kq * 262144 + base + (gg * 16 + jl) * 64 + b];
        g4[gg] = v + bs[gg * 1024 + rt * 16 + jl];
    }
    float si = 1.f / (1.f + expf(-g4[0]));
    float sf = 1.f / (1.f + expf(-g4[1]));
    float so = 1.f / (1.f + expf(-g4[3]));
    float tg = tanhf(g4[2]);
    int j = rt * 16 + jl;
    int ci = b * 1024 + j;
    float cn = sf * c[ci] + si * tg;
    c[ci] = cn;
    float hn = so * tanhf(cn);
    unsigned short hi = bf_hi(hn);
    unsigned short lo = bf_hi(hn - bf_f(hi));
    int kt = j >> 6, kl = j & 63;
    int s = kl >> 5, gq = (kl >> 3) & 3, off = kl & 7;
    int chunk = s * 256 + (b >> 4) * 64 + gq * 16 + (b & 15);
    char* d = Hdst + kt * 16384 + chunk * 16 + off * 2;
    *(unsigned short*)d = hi;
    *(unsigned short*)(d + 8192) = lo;
}

// ---------------- logits GEMM + raw store + softmax partials ----------------
__global__ __launch_bounds__(256) void k_logits(
    const char* __restrict__ WObase, const float* __restrict__ bout,
    const char* __restrict__ A, float* __restrict__ out, int tstep,
    float* __restrict__ pm, float* __restrict__ ps, int* __restrict__ pa) {
    __shared__ __align__(16) char smem[65536];
    const int tid = threadIdx.x;
    const int v0 = blockIdx.x * 64;
    const char* Wsrc = WObase + (size_t)blockIdx.x * 262144;
    f32x4 acc[4];
    #pragma unroll
    for (int i = 0; i < 4; ++i) acc[i] = (f32x4){0.f, 0.f, 0.f, 0.f};
    gemm_core<16>(Wsrc, A, smem, tid, acc);
    const int l = tid & 63, w = tid >> 6, g = l >> 4, n = l & 15;
    int bidx = v0 + w * 16 + g * 4; if (bidx > VV - 4) bidx = VV - 4;
    f32x4 bb4 = *(const f32x4*)&bout[bidx];
    float* gl = (float*)smem;   // [64 b][68]
    #pragma unroll
    for (int bg = 0; bg < 4; ++bg)
        #pragma unroll
        for (int p = 0; p < 4; ++p)
            gl[(bg * 16 + n) * 68 + w * 16 + g * 4 + p] = acc[bg][p] + bb4[p];
    __syncthreads();
    int b = tid >> 2, vq = tid & 3;
    float m = -INFINITY, ssum = 0.f; int am = VV;
    if (v0 + vq * 16 < VV) {
        size_t ob = ((size_t)b * TT + tstep) * VV + v0 + vq * 16;
        #pragma unroll
        for (int e4 = 0; e4 < 4; ++e4) {
            f32x4 vv = *(const f32x4*)&gl[b * 68 + vq * 16 + e4 * 4];
            *(f32x4*)&out[ob + e4 * 4] = vv;
            #pragma unroll
            for (int p = 0; p < 4; ++p)
                merge3(m, ssum, am, vv[p], 1.f, v0 + vq * 16 + e4 * 4 + p);
        }
    }
    #pragma unroll
    for (int off = 1; off < 4; off <<= 1) {
        float m2 = __shfl_xor(m, off, 64);
        float s2 = __shfl_xor(ssum, off, 64);
        int a2 = __shfl_xor(am, off, 64);
        merge3(m, ssum, am, m2, s2, a2);
    }
    if (vq == 0) {
        pm[b * PSTRIDE + blockIdx.x] = m;
        ps[b * PSTRIDE + blockIdx.x] = ssum;
        pa[b * PSTRIDE + blockIdx.x] = am;
    }
}

// ---------------- reduce + argmax + fused embedding gather ----------------
__global__ void k_reduce(const float* __restrict__ pm, const float* __restrict__ ps,
                         const int* __restrict__ pa, float* __restrict__ lse_all,
                         int t, const float* __restrict__ Wemb, char* __restrict__ X1) {
    int b = blockIdx.x;
    int tid = threadIdx.x;   // 256
    float m = -INFINITY, s = 0.f; int a = VV;
    for (int i = tid; i < NBT; i += 256)
        merge3(m, s, a, pm[(size_t)b * PSTRIDE + i], ps[(size_t)b * PSTRIDE + i],
               pa[(size_t)b * PSTRIDE + i]);
    #pragma unroll
    for (int off = 1; off < 64; off <<= 1) {
        float m2 = __shfl_xor(m, off, 64);
        float s2 = __shfl_xor(s, off, 64);
        int   a2 = __shfl_xor(a, off, 64);
        merge3(m, s, a, m2, s2, a2);
    }
    __shared__ float sm[4], ss[4]; __shared__ int sa[4]; __shared__ int stok;
    if ((tid & 63) == 0) { sm[tid >> 6] = m; ss[tid >> 6] = s; sa[tid >> 6] = a; }
    __syncthreads();
    if (tid == 0) {
        for (int w = 1; w < 4; ++w) merge3(m, s, a, sm[w], ss[w], sa[w]);
        lse_all[t * 64 + b] = m + logf(s);
        stok = a;
    }
    __syncthreads();
    emb_write(X1, Wemb, stok, b, tid);
}

// ---------------- final pass: row0 one-hot + lse subtract ----------------
__global__ void k_fix(float* __restrict__ out, const float* __restrict__ lse_all) {
    int v = blockIdx.x * 256 + threadIdx.x;
    int t = blockIdx.y, b = blockIdx.z;
    if (v >= VV) return;
    size_t o = ((size_t)b * TT + t) * VV + v;
    if (t == 0) out[o] = (v == 1) ? 1.f : 0.f;
    else out[o] -= lse_all[t * 64 + b];
}

extern "C" void kernel_launch(void* const* d_in, const int* in_sizes, int n_in,
                              void* d_out, int out_size, void* d_ws, size_t ws_size,
                              hipStream_t stream) {
    const float* img   = (const float*)d_in[0];
    const float* Wemb  = (const float*)d_in[1];
    const float* Wih1  = (const float*)d_in[2];
    const float* Whh1  = (const float*)d_in[3];
    const float* bih1  = (const float*)d_in[4];
    const float* bhh1  = (const float*)d_in[5];
    const float* Wih2  = (const float*)d_in[6];
    const float* Whh2  = (const float*)d_in[7];
    const float* bih2  = (const float*)d_in[8];
    const float* bhh2  = (const float*)d_in[9];
    const float* Wout  = (const float*)d_in[10];
    const float* bout  = (const float*)d_in[11];
    float* out = (float*)d_out;
    char*  wsb = (char*)d_ws;

    char* W1 = wsb + OFF_W1;
    char* W2 = wsb + OFF_W2;
    char* WO = wsb + OFF_WO;
    char* X1 = wsb + OFF_X1;
    float* c1 = (float*)(wsb + OFF_C1);
    float* c2 = (float*)(wsb + OFF_C2);
    float* P  = (float*)(wsb + OFF_P);
    float* pm = (float*)(wsb + OFF_PM);
    float* ps = (float*)(wsb + OFF_PS);
    int*   pa = (int*)(wsb + OFF_PA);
    float* lse_all = (float*)(wsb + OFF_LSE);
    float* bs = (float*)(wsb + OFF_BS);
    auto Hb = [&](size_t base, int bank) { return wsb + base + (size_t)bank * 262144; };

    k_conv_cell<<<dim3(4096, 2), 256, 0, stream>>>(Wih1, Whh1, Wih2, Whh2, wsb);
    k_conv_out<<<15008, 256, 0, stream>>>(Wout, wsb);
    k_conv_img<<<16, 256, 0, stream>>>(img, wsb);
    k_prep<<<1184, 256, 0, stream>>>(wsb, bih1, bhh1, bih2, bhh2);

    int cur = 0;
    // pre-loop step: x = [img | 0], h/c start at zero (banks 0)
    k_cellg<<<256, 256, 0, stream>>>(W1, X1, Hb(OFF_H1, cur), P);
    k_emb0<<<64, 256, 0, stream>>>(Wemb, wsb);   // emb(START) for step t=1
    k_act<<<dim3(64, 4), 256, 0, stream>>>(P, bs, c1, Hb(OFF_H1, cur ^ 1));
    k_cellg<<<256, 256, 0, stream>>>(W2, Hb(OFF_H1, cur ^ 1), Hb(OFF_H2, cur), P);
    k_act<<<dim3(64, 4), 256, 0, stream>>>(P, bs + 4096, c2, Hb(OFF_H2, cur ^ 1));
    cur = 1;

    for (int t = 1; t < TT; ++t) {
        k_cellg<<<256, 256, 0, stream>>>(W1, X1, Hb(OFF_H1, cur), P);
        k_act<<<dim3(64, 4), 256, 0, stream>>>(P, bs, c1, Hb(OFF_H1, cur ^ 1));
        k_cellg<<<256, 256, 0, stream>>>(W2, Hb(OFF_H1, cur ^ 1), Hb(OFF_H2, cur), P);
        k_act<<<dim3(64, 4), 256, 0, stream>>>(P, bs + 4096, c2, Hb(OFF_H2, cur ^ 1));
        k_logits<<<NBT, 256, 0, stream>>>(WO, bout, Hb(OFF_H2, cur ^ 1),
                                          out, t, pm, ps, pa);
        k_reduce<<<64, 256, 0, stream>>>(pm, ps, pa, lse_all, t, Wemb, X1);
        cur ^= 1;
    }
    k_fix<<<dim3(118, TT, BB), 256, 0, stream>>>(out, lse_all);
}